// Round 23
// baseline (142.050 us; speedup 1.0000x reference)
//
#include <hip/hip_runtime.h>

#define M_CODES 512
#define D_EMB 128
#define D4 32
#define MARGIN 5e-5f
#define SCHUNK 1024   // tokens per scatter chunk

typedef short bf16x8 __attribute__((ext_vector_type(8)));
typedef float f32x4 __attribute__((ext_vector_type(4)));

__device__ __forceinline__ unsigned short f2bf(float f) {  // RNE f32->bf16
    unsigned u = __float_as_uint(f);
    u += 0x7fffu + ((u >> 16) & 1u);
    return (unsigned short)(u >> 16);
}
__device__ __forceinline__ float bf2f(unsigned short h) {
    return __uint_as_float(((unsigned)h) << 16);
}

// numpy pairwise sum (n=128): 8 strided accumulators + tree. (R6-validated.)
__device__ __forceinline__ float np_pairwise_sumsq128(const float* __restrict__ a,
                                                      float scale) {
    float r[8];
#pragma unroll
    for (int j = 0; j < 8; ++j) {
        float v = __fmul_rn(a[j], scale);
        r[j] = __fmul_rn(v, v);
    }
    for (int i = 8; i < 128; i += 8) {
#pragma unroll
        for (int j = 0; j < 8; ++j) {
            float v = __fmul_rn(a[i + j], scale);
            r[j] = __fadd_rn(r[j], __fmul_rn(v, v));
        }
    }
    return __fadd_rn(__fadd_rn(__fadd_rn(r[0], r[1]), __fadd_rn(r[2], r[3])),
                     __fadd_rn(__fadd_rn(r[4], r[5]), __fadd_rn(r[6], r[7])));
}

// kSZ: parallel setup (R17-validated).
__global__ __launch_bounds__(256) void kSZ(const float* __restrict__ emb,
                                           float* __restrict__ sumE,
                                           float* __restrict__ embT,
                                           unsigned short* __restrict__ ebh,
                                           unsigned short* __restrict__ ebl,
                                           float* __restrict__ accc,
                                           int* __restrict__ flagCnt) {
    int tid = threadIdx.x, wid = tid >> 6, lane = tid & 63;
    int m = blockIdx.x * 4 + wid;            // 0..511
    int gi = blockIdx.x * 256 + tid;
    if (gi < M_CODES) accc[gi] = 0.f;
    if (gi == 0) *flagCnt = 0;
    const float* er = emb + (size_t)m * D_EMB;
    float r = 0.f;
    if (lane < 8) {
        float v = __fmul_rn(er[lane], 1.0f);
        r = __fmul_rn(v, v);
        for (int i = 1; i < 16; ++i) {
            float w = __fmul_rn(er[8 * i + lane], 1.0f);
            r = __fadd_rn(r, __fmul_rn(w, w));
        }
    }
    float s1 = __fadd_rn(r, __shfl_xor(r, 1, 64));
    float s2 = __fadd_rn(s1, __shfl_xor(s1, 2, 64));
    float s3 = __fadd_rn(s2, __shfl_xor(s2, 4, 64));
    if (lane == 0) sumE[m] = s3;
#pragma unroll
    for (int dd = lane; dd < D_EMB; dd += 64) {
        float e = er[dd];
        embT[dd * M_CODES + m] = e;
        unsigned short hh = f2bf(e);
        ebh[(size_t)m * D_EMB + dd] = hh;
        ebl[(size_t)m * D_EMB + dd] = f2bf(e - bf2f(hh));
    }
}

// kA: split-bf16 MFMA + LDS-staged codebook, 32-code tiles + T14 async-stage
// split. (R22-validated: fell out of top-5.)
__global__ __launch_bounds__(256) void kA(const float* __restrict__ x,
                                          const float* __restrict__ xmask,
                                          const unsigned short* __restrict__ ebh,
                                          const unsigned short* __restrict__ ebl,
                                          const float* __restrict__ sumE,
                                          int* __restrict__ idx_out,
                                          int* __restrict__ flagCnt,
                                          int* __restrict__ flagList,
                                          float* __restrict__ lossW,
                                          float* __restrict__ maskW, int N) {
    __shared__ unsigned short hb[2][4096];   // 8 KB per buf: 32 codes x 128d
    __shared__ unsigned short lb[2][4096];
    __shared__ float xnS[4][32], mkS[4][32];
    int tid = threadIdx.x;
    int wid = tid >> 6, lane = tid & 63;
    int m = lane & 15, kg = lane >> 4;
    int tok0 = blockIdx.x * 128 + wid * 32;

    bf16x8 ah0[4], al0[4], ah1[4], al1[4];
    float xn0 = 0.f, xn1 = 0.f;
    float mk0 = xmask[tok0 + m], mk1 = xmask[tok0 + 16 + m];
#pragma unroll
    for (int ks = 0; ks < 4; ++ks) {
        const float4* p0 = reinterpret_cast<const float4*>(
            x + (size_t)(tok0 + m) * D_EMB + ks * 32 + kg * 8);
        const float4* p1 = reinterpret_cast<const float4*>(
            x + (size_t)(tok0 + 16 + m) * D_EMB + ks * 32 + kg * 8);
        float4 a0 = p0[0], a1 = p0[1], c0 = p1[0], c1 = p1[1];
        float e0[8] = {a0.x, a0.y, a0.z, a0.w, a1.x, a1.y, a1.z, a1.w};
        float e1[8] = {c0.x, c0.y, c0.z, c0.w, c1.x, c1.y, c1.z, c1.w};
        bf16x8 h0, l0, h1, l1;
#pragma unroll
        for (int j = 0; j < 8; ++j) {
            float v0 = e0[j] * mk0;
            xn0 = fmaf(v0, v0, xn0);
            unsigned short hh0 = f2bf(v0);
            h0[j] = (short)hh0;
            l0[j] = (short)f2bf(v0 - bf2f(hh0));
            float v1 = e1[j] * mk1;
            xn1 = fmaf(v1, v1, xn1);
            unsigned short hh1 = f2bf(v1);
            h1[j] = (short)hh1;
            l1[j] = (short)f2bf(v1 - bf2f(hh1));
        }
        ah0[ks] = h0; al0[ks] = l0; ah1[ks] = h1; al1[ks] = l1;
    }
    xn0 += __shfl_xor(xn0, 16, 64);
    xn0 += __shfl_xor(xn0, 32, 64);
    xn1 += __shfl_xor(xn1, 16, 64);
    xn1 += __shfl_xor(xn1, 32, 64);
    if (kg == 0) {
        xnS[wid][m] = xn0; mkS[wid][m] = mk0;
        xnS[wid][16 + m] = xn1; mkS[wid][16 + m] = mk1;
    }

    float b1[2][4], b2[2][4];
    int bi[2][4];
#pragma unroll
    for (int tt = 0; tt < 2; ++tt)
#pragma unroll
        for (int r = 0; r < 4; ++r) {
            b1[tt][r] = 3.4e38f; b2[tt][r] = 3.4e38f; bi[tt][r] = 0x7fffffff;
        }

    int mo = tid >> 4, sl = tid & 15;
    int dstIdx = mo * 128 + (sl >> 3) * 64 + ((sl & 7) ^ (mo & 7)) * 8;  // ushorts
    float4 sh0, sv0, sh1, sv1;
#define LOADREGS(t)                                                            \
    {                                                                          \
        sh0 = *reinterpret_cast<const float4*>(                                \
            ebh + (size_t)((t) * 32 + mo) * D_EMB + sl * 8);                   \
        sv0 = *reinterpret_cast<const float4*>(                                \
            ebl + (size_t)((t) * 32 + mo) * D_EMB + sl * 8);                   \
        sh1 = *reinterpret_cast<const float4*>(                                \
            ebh + (size_t)((t) * 32 + 16 + mo) * D_EMB + sl * 8);              \
        sv1 = *reinterpret_cast<const float4*>(                                \
            ebl + (size_t)((t) * 32 + 16 + mo) * D_EMB + sl * 8);              \
    }
#define WRITEB(b)                                                              \
    {                                                                          \
        *reinterpret_cast<float4*>(&hb[b][dstIdx]) = sh0;                      \
        *reinterpret_cast<float4*>(&lb[b][dstIdx]) = sv0;                      \
        *reinterpret_cast<float4*>(&hb[b][2048 + dstIdx]) = sh1;               \
        *reinterpret_cast<float4*>(&lb[b][2048 + dstIdx]) = sv1;               \
    }

    LOADREGS(0);
    WRITEB(0);
    __syncthreads();
    for (int t = 0; t < 16; ++t) {
        int cur = t & 1;
        if (t < 15) LOADREGS(t + 1);   // issue early (T14)
#pragma unroll
        for (int sub = 0; sub < 2; ++sub) {
            bf16x8 bh[4], bl[4];
#pragma unroll
            for (int ks = 0; ks < 4; ++ks) {
                int off = sub * 2048 + m * 128 + (ks >> 1) * 64 +
                          ((((ks & 1) * 4 + kg)) ^ (m & 7)) * 8;
                bh[ks] = *reinterpret_cast<const bf16x8*>(&hb[cur][off]);
                bl[ks] = *reinterpret_cast<const bf16x8*>(&lb[cur][off]);
            }
            f32x4 accA0 = {0.f, 0.f, 0.f, 0.f}, accB0 = {0.f, 0.f, 0.f, 0.f};
            f32x4 accA1 = {0.f, 0.f, 0.f, 0.f}, accB1 = {0.f, 0.f, 0.f, 0.f};
#pragma unroll
            for (int ks = 0; ks < 2; ++ks) {
                accA0 = __builtin_amdgcn_mfma_f32_16x16x32_bf16(ah0[ks], bh[ks], accA0, 0, 0, 0);
                accA0 = __builtin_amdgcn_mfma_f32_16x16x32_bf16(al0[ks], bh[ks], accA0, 0, 0, 0);
                accA0 = __builtin_amdgcn_mfma_f32_16x16x32_bf16(ah0[ks], bl[ks], accA0, 0, 0, 0);
                accA1 = __builtin_amdgcn_mfma_f32_16x16x32_bf16(ah1[ks], bh[ks], accA1, 0, 0, 0);
                accA1 = __builtin_amdgcn_mfma_f32_16x16x32_bf16(al1[ks], bh[ks], accA1, 0, 0, 0);
                accA1 = __builtin_amdgcn_mfma_f32_16x16x32_bf16(ah1[ks], bl[ks], accA1, 0, 0, 0);
            }
#pragma unroll
            for (int ks = 2; ks < 4; ++ks) {
                accB0 = __builtin_amdgcn_mfma_f32_16x16x32_bf16(ah0[ks], bh[ks], accB0, 0, 0, 0);
                accB0 = __builtin_amdgcn_mfma_f32_16x16x32_bf16(al0[ks], bh[ks], accB0, 0, 0, 0);
                accB0 = __builtin_amdgcn_mfma_f32_16x16x32_bf16(ah0[ks], bl[ks], accB0, 0, 0, 0);
                accB1 = __builtin_amdgcn_mfma_f32_16x16x32_bf16(ah1[ks], bh[ks], accB1, 0, 0, 0);
                accB1 = __builtin_amdgcn_mfma_f32_16x16x32_bf16(al1[ks], bh[ks], accB1, 0, 0, 0);
                accB1 = __builtin_amdgcn_mfma_f32_16x16x32_bf16(ah1[ks], bl[ks], accB1, 0, 0, 0);
            }
            int c = t * 32 + sub * 16 + m;
            float sE = sumE[c];
#pragma unroll
            for (int r = 0; r < 4; ++r) {
                float s0 = fmaf(-2.f, accA0[r] + accB0[r], sE);
                if (s0 < b1[0][r]) { b2[0][r] = b1[0][r]; b1[0][r] = s0; bi[0][r] = c; }
                else if (s0 < b2[0][r]) b2[0][r] = s0;
                float s1 = fmaf(-2.f, accA1[r] + accB1[r], sE);
                if (s1 < b1[1][r]) { b2[1][r] = b1[1][r]; b1[1][r] = s1; bi[1][r] = c; }
                else if (s1 < b2[1][r]) b2[1][r] = s1;
            }
        }
        if (t < 15) WRITEB(cur ^ 1);   // write late
        __syncthreads();
    }
#undef LOADREGS
#undef WRITEB
#pragma unroll
    for (int off = 1; off <= 8; off <<= 1) {
#pragma unroll
        for (int tt = 0; tt < 2; ++tt)
#pragma unroll
            for (int r = 0; r < 4; ++r) {
                float o1 = __shfl_xor(b1[tt][r], off, 64);
                float o2 = __shfl_xor(b2[tt][r], off, 64);
                int oi = __shfl_xor(bi[tt][r], off, 64);
                if (o1 < b1[tt][r] || (o1 == b1[tt][r] && oi < bi[tt][r])) {
                    b2[tt][r] = fminf(b1[tt][r], o2); b1[tt][r] = o1; bi[tt][r] = oi;
                } else {
                    b2[tt][r] = fminf(b2[tt][r], o1);
                }
            }
    }
    float liS = 0.f, mkT = 0.f;
#pragma unroll
    for (int tt = 0; tt < 2; ++tt)
#pragma unroll
        for (int r = 0; r < 4; ++r) {
            int row = kg * 4 + r;
            float mkr = mkS[wid][tt * 16 + row], xnr = xnS[wid][tt * 16 + row];
            liS += mkr * mkr * (xnr + b1[tt][r]);
            mkT += mkr;
            if (m == 0) {
                int tokr = tok0 + tt * 16 + row;
                idx_out[tokr] = bi[tt][r];
                if (b2[tt][r] - b1[tt][r] < MARGIN) {
                    int pp = atomicAdd(flagCnt, 1);
                    flagList[pp] = tokr;
                }
            }
        }
    liS += __shfl_xor(liS, 16, 64);
    liS += __shfl_xor(liS, 32, 64);
    mkT += __shfl_xor(mkT, 16, 64);
    mkT += __shfl_xor(mkT, 32, 64);
    if (lane == 0) {
        int grp = blockIdx.x * 4 + wid;
        lossW[grp] = liS;
        maskW[grp] = mkT;
    }
}

// kF: bit-exact np-f32 rescan, one token per wave. (R21-validated.)
__global__ __launch_bounds__(256) void kF(const float* __restrict__ x,
                                          const float* __restrict__ xmask,
                                          const float* __restrict__ embT,
                                          const float* __restrict__ sumE,
                                          const int* __restrict__ flagCnt,
                                          const int* __restrict__ flagList,
                                          int* __restrict__ idx_out) {
    int wave = (blockIdx.x * 256 + threadIdx.x) >> 6;
    int lane = threadIdx.x & 63;
    int nW = gridDim.x * 4;
    int cnt = *flagCnt;
    for (int j = wave; j < cnt; j += nW) {
        int t = flagList[j];
        float mk = xmask[t];
        const float* xr = x + (size_t)t * D_EMB;
        float sx = np_pairwise_sumsq128(xr, mk);
        float acc[8];
#pragma unroll
        for (int cb = 0; cb < 8; ++cb) acc[cb] = 0.f;
        for (int i = 0; i < D_EMB; ++i) {
            float xi = __fmul_rn(xr[i], mk);
#pragma unroll
            for (int cb = 0; cb < 8; ++cb)
                acc[cb] = __fmaf_rn(xi, embT[i * M_CODES + cb * 64 + lane], acc[cb]);
        }
        float best = 3.4e38f;
        int bq = 0x7fffffff;
#pragma unroll
        for (int cb = 0; cb < 8; ++cb) {
            int c = cb * 64 + lane;
            float d = __fsub_rn(__fadd_rn(sumE[c], sx), __fmul_rn(2.f, acc[cb]));
            if (d < best || (d == best && c < bq)) { best = d; bq = c; }
        }
#pragma unroll
        for (int off = 32; off > 0; off >>= 1) {
            float s2 = __shfl_xor(best, off, 64);
            int i2 = __shfl_xor(bq, off, 64);
            if (s2 < best || (s2 == best && i2 < bq)) { best = s2; bq = i2; }
        }
        if (lane == 0) idx_out[t] = bq;
    }
}

// kQ: pure gather q_st = emb[idx]*mask (R7-proven mapping). 32 lanes write one
// 512 B row -> fully coalesced; no atomics. (R22: q_st's 64 B fragment writes
// inside kScat throttled write combining.)
__global__ __launch_bounds__(256) void kQ(const float* __restrict__ emb,
                                          const float* __restrict__ xmask,
                                          const int* __restrict__ idx,
                                          float* __restrict__ q_st, int N) {
    int g = blockIdx.x * 256 + threadIdx.x;
    int t = g >> 5;
    int d4 = g & 31;
    if (t < N) {
        int id = idx[t];
        float mk = xmask[t];
        float4 ev = reinterpret_cast<const float4*>(emb)[(size_t)id * D4 + d4];
        float4 o;
        o.x = ev.x * mk; o.y = ev.y * mk; o.z = ev.z * mk; o.w = ev.w * mk;
        reinterpret_cast<float4*>(q_st)[(size_t)t * D4 + d4] = o;
    }
}

// kScat: LDS-accumulated scatter (no q_st). R22 fix: 512 threads/block ->
// 16 waves/CU (was ~5; latency-bound at Occupancy 16%). Thread = (tl 0..127
// tokens, dl 0..3 float4-of-slice); 4 LDS atomics per thread per token.
__global__ __launch_bounds__(512) void kScat(const float* __restrict__ x,
                                             const float* __restrict__ xmask,
                                             const int* __restrict__ idx,
                                             float* __restrict__ partialD,
                                             float* __restrict__ accc,
                                             int N, int nch) {
    __shared__ float accD[16 * M_CODES];   // [dd][code]
    __shared__ float accC[M_CODES];
    int bid = blockIdx.x;
    int q = bid / nch, ch = bid - q * nch;   // q = dim-slice 0..7
    int tid = threadIdx.x;
    for (int i = tid; i < 16 * M_CODES; i += 512) accD[i] = 0.f;
    if (q == 0)
        for (int i = tid; i < M_CODES; i += 512) accC[i] = 0.f;
    __syncthreads();
    int tl = tid >> 2, dl = tid & 3;
    int base = ch * SCHUNK;
    for (int it = 0; it < SCHUNK / 128; ++it) {
        int t = base + it * 128 + tl;
        if (t < N) {
            int id = idx[t];
            float mk = xmask[t];
            float4 xv = *reinterpret_cast<const float4*>(
                x + (size_t)t * D_EMB + q * 16 + dl * 4);
            int d0 = dl * 4;
            atomicAdd(&accD[(d0 + 0) * M_CODES + id], xv.x * mk);
            atomicAdd(&accD[(d0 + 1) * M_CODES + id], xv.y * mk);
            atomicAdd(&accD[(d0 + 2) * M_CODES + id], xv.z * mk);
            atomicAdd(&accD[(d0 + 3) * M_CODES + id], xv.w * mk);
            if (q == 0 && dl == 0) atomicAdd(&accC[id], 1.f);
        }
    }
    __syncthreads();
    float* pD = partialD + (size_t)bid * (16 * M_CODES);
    for (int i = tid; i < 16 * M_CODES; i += 512) pD[i] = accD[i];
    if (q == 0)
        for (int i = tid; i < M_CODES; i += 512) atomicAdd(&accc[i], accC[i]);
}

// kWD2: fused finalize (R22-validated): per-block nsum recompute, partial
// reduce + EMA + divide; block 0 finalizes loss.
__global__ __launch_bounds__(256) void kWD2(const float* __restrict__ partialD,
                                            const float* __restrict__ ema_w,
                                            const float* __restrict__ counts,
                                            const float* __restrict__ ema_count,
                                            const float* __restrict__ lossP,
                                            const float* __restrict__ maskP,
                                            float* __restrict__ new_w,
                                            float* __restrict__ new_emb,
                                            float* __restrict__ new_cnt,
                                            float* __restrict__ loss_out,
                                            int nch, int nP) {
    __shared__ float red[256];
    int tid = threadIdx.x;
    float part = 0.999f * ema_count[tid] + 0.001f * counts[tid];
    part += 0.999f * ema_count[tid + 256] + 0.001f * counts[tid + 256];
    red[tid] = part;
    __syncthreads();
#pragma unroll
    for (int s = 128; s > 0; s >>= 1) {
        if (tid < s) red[tid] += red[tid + s];
        __syncthreads();
    }
    float nsum = red[0];
    __syncthreads();

    int i = blockIdx.x * 256 + tid;   // 65536 elements
    int c = i & 511;                  // code (fastest)
    int d = i >> 9;                   // dim 0..127
    int q = d >> 4, dd = d & 15;
    float raw = 0.999f * ema_count[c] + 0.001f * counts[c];
    float norm = (raw + 1e-5f) / (nsum + (float)M_CODES * 1e-5f) * nsum;
    float s = 0.f;
    for (int ch = 0; ch < nch; ++ch)
        s += partialD[(size_t)(q * nch + ch) * (16 * M_CODES) + dd * M_CODES + c];
    size_t o = (size_t)c * D_EMB + d;
    float w = 0.999f * ema_w[o] + 0.001f * s;
    new_w[o] = w;
    new_emb[o] = w / norm;
    if (d == 0) new_cnt[c] = norm;

    if (blockIdx.x == 0) {
        float lp = 0.f, mp = 0.f;
        for (int j = tid; j < nP; j += 256) { lp += lossP[j]; mp += maskP[j]; }
        red[tid] = lp;
        __syncthreads();
#pragma unroll
        for (int ss = 128; ss > 0; ss >>= 1) {
            if (tid < ss) red[tid] += red[tid + ss];
            __syncthreads();
        }
        float S = red[0];
        __syncthreads();
        red[tid] = mp;
        __syncthreads();
#pragma unroll
        for (int ss = 128; ss > 0; ss >>= 1) {
            if (tid < ss) red[tid] += red[tid + ss];
            __syncthreads();
        }
        if (tid == 0) loss_out[0] = 0.25f * S / (red[0] * (float)D_EMB);
    }
}

extern "C" void kernel_launch(void* const* d_in, const int* in_sizes, int n_in,
                              void* d_out, int out_size, void* d_ws, size_t ws_size,
                              hipStream_t stream) {
    const float* x = (const float*)d_in[0];
    const float* xmask = (const float*)d_in[1];
    const float* emb = (const float*)d_in[2];
    const float* ema_count = (const float*)d_in[3];
    const float* ema_weight = (const float*)d_in[4];
    int N = in_sizes[0] / D_EMB;

    float* out = (float*)d_out;
    float* q_st = out;
    float* loss = out + (size_t)N * D_EMB;
    float* new_emb = loss + 1;
    float* new_cnt = new_emb + M_CODES * D_EMB;
    float* new_w = new_cnt + M_CODES;

    int nGrp = N / 32;                         // 2048 wave groups
    int nch = (N + SCHUNK - 1) / SCHUNK;       // 64
    float* fws = (float*)d_ws;
    int* idx = (int*)fws;                      // N
    float* counts = fws + N;                   // 512 (accc)
    float* norm = counts + M_CODES;            // 512 (unused; layout keep)
    float* lossP = norm + M_CODES;             // nGrp
    float* maskP = lossP + nGrp;               // nGrp
    float* sumE = maskP + nGrp;                // 512
    int* flagCnt = (int*)(sumE + M_CODES);     // 4
    int* flagList = flagCnt + 4;               // N
    float* embT = (float*)(flagList + N);      // 65536
    unsigned short* ebh = (unsigned short*)(embT + M_CODES * D_EMB);  // 65536 u16
    unsigned short* ebl = ebh + M_CODES * D_EMB;                      // 65536 u16
    float* partialD = (float*)(ebl + M_CODES * D_EMB);  // 8*nch*16*512 f32 (16MB)

    hipLaunchKernelGGL(kSZ, dim3(128), dim3(256), 0, stream,
                       emb, sumE, embT, ebh, ebl, counts, flagCnt);
    hipLaunchKernelGGL(kA, dim3(N / 128), dim3(256), 0, stream, x, xmask, ebh,
                       ebl, sumE, idx, flagCnt, flagList, lossP, maskP, N);
    hipLaunchKernelGGL(kF, dim3(1024), dim3(256), 0, stream, x, xmask, embT, sumE,
                       flagCnt, flagList, idx);
    hipLaunchKernelGGL(kQ, dim3((N * 32 + 255) / 256), dim3(256), 0, stream,
                       emb, xmask, idx, q_st, N);
    hipLaunchKernelGGL(kScat, dim3(8 * nch), dim3(512), 0, stream, x, xmask,
                       idx, partialD, counts, N, nch);
    hipLaunchKernelGGL(kWD2, dim3(M_CODES * D_EMB / 256), dim3(256), 0, stream,
                       partialD, ema_weight, counts, ema_count, lossP, maskP,
                       new_w, new_emb, new_cnt, loss, nch, nGrp);
}

// Round 24
// 135.165 us; speedup vs baseline: 1.0509x; 1.0509x over previous
//
#include <hip/hip_runtime.h>

#define M_CODES 512
#define D_EMB 128
#define D4 32
#define MARGIN 5e-5f
#define SCHUNK 1024   // tokens per scatter chunk
#define ADSTRIDE 513  // accD row stride (bank de-alias)

typedef short bf16x8 __attribute__((ext_vector_type(8)));
typedef float f32x4 __attribute__((ext_vector_type(4)));

__device__ __forceinline__ unsigned short f2bf(float f) {  // RNE f32->bf16
    unsigned u = __float_as_uint(f);
    u += 0x7fffu + ((u >> 16) & 1u);
    return (unsigned short)(u >> 16);
}
__device__ __forceinline__ float bf2f(unsigned short h) {
    return __uint_as_float(((unsigned)h) << 16);
}

// numpy pairwise sum (n=128): 8 strided accumulators + tree. (R6-validated.)
__device__ __forceinline__ float np_pairwise_sumsq128(const float* __restrict__ a,
                                                      float scale) {
    float r[8];
#pragma unroll
    for (int j = 0; j < 8; ++j) {
        float v = __fmul_rn(a[j], scale);
        r[j] = __fmul_rn(v, v);
    }
    for (int i = 8; i < 128; i += 8) {
#pragma unroll
        for (int j = 0; j < 8; ++j) {
            float v = __fmul_rn(a[i + j], scale);
            r[j] = __fadd_rn(r[j], __fmul_rn(v, v));
        }
    }
    return __fadd_rn(__fadd_rn(__fadd_rn(r[0], r[1]), __fadd_rn(r[2], r[3])),
                     __fadd_rn(__fadd_rn(r[4], r[5]), __fadd_rn(r[6], r[7])));
}

// kSZ: parallel setup (R17-validated).
__global__ __launch_bounds__(256) void kSZ(const float* __restrict__ emb,
                                           float* __restrict__ sumE,
                                           float* __restrict__ embT,
                                           unsigned short* __restrict__ ebh,
                                           unsigned short* __restrict__ ebl,
                                           float* __restrict__ accc,
                                           int* __restrict__ flagCnt) {
    int tid = threadIdx.x, wid = tid >> 6, lane = tid & 63;
    int m = blockIdx.x * 4 + wid;            // 0..511
    int gi = blockIdx.x * 256 + tid;
    if (gi < M_CODES) accc[gi] = 0.f;
    if (gi == 0) *flagCnt = 0;
    const float* er = emb + (size_t)m * D_EMB;
    float r = 0.f;
    if (lane < 8) {
        float v = __fmul_rn(er[lane], 1.0f);
        r = __fmul_rn(v, v);
        for (int i = 1; i < 16; ++i) {
            float w = __fmul_rn(er[8 * i + lane], 1.0f);
            r = __fadd_rn(r, __fmul_rn(w, w));
        }
    }
    float s1 = __fadd_rn(r, __shfl_xor(r, 1, 64));
    float s2 = __fadd_rn(s1, __shfl_xor(s1, 2, 64));
    float s3 = __fadd_rn(s2, __shfl_xor(s2, 4, 64));
    if (lane == 0) sumE[m] = s3;
#pragma unroll
    for (int dd = lane; dd < D_EMB; dd += 64) {
        float e = er[dd];
        embT[dd * M_CODES + m] = e;
        unsigned short hh = f2bf(e);
        ebh[(size_t)m * D_EMB + dd] = hh;
        ebl[(size_t)m * D_EMB + dd] = f2bf(e - bf2f(hh));
    }
}

// kA: split-bf16 MFMA + LDS-staged codebook, 32-code tiles + T14 async-stage
// split. (R22-validated.)
__global__ __launch_bounds__(256) void kA(const float* __restrict__ x,
                                          const float* __restrict__ xmask,
                                          const unsigned short* __restrict__ ebh,
                                          const unsigned short* __restrict__ ebl,
                                          const float* __restrict__ sumE,
                                          int* __restrict__ idx_out,
                                          int* __restrict__ flagCnt,
                                          int* __restrict__ flagList,
                                          float* __restrict__ lossW,
                                          float* __restrict__ maskW, int N) {
    __shared__ unsigned short hb[2][4096];   // 8 KB per buf: 32 codes x 128d
    __shared__ unsigned short lb[2][4096];
    __shared__ float xnS[4][32], mkS[4][32];
    int tid = threadIdx.x;
    int wid = tid >> 6, lane = tid & 63;
    int m = lane & 15, kg = lane >> 4;
    int tok0 = blockIdx.x * 128 + wid * 32;

    bf16x8 ah0[4], al0[4], ah1[4], al1[4];
    float xn0 = 0.f, xn1 = 0.f;
    float mk0 = xmask[tok0 + m], mk1 = xmask[tok0 + 16 + m];
#pragma unroll
    for (int ks = 0; ks < 4; ++ks) {
        const float4* p0 = reinterpret_cast<const float4*>(
            x + (size_t)(tok0 + m) * D_EMB + ks * 32 + kg * 8);
        const float4* p1 = reinterpret_cast<const float4*>(
            x + (size_t)(tok0 + 16 + m) * D_EMB + ks * 32 + kg * 8);
        float4 a0 = p0[0], a1 = p0[1], c0 = p1[0], c1 = p1[1];
        float e0[8] = {a0.x, a0.y, a0.z, a0.w, a1.x, a1.y, a1.z, a1.w};
        float e1[8] = {c0.x, c0.y, c0.z, c0.w, c1.x, c1.y, c1.z, c1.w};
        bf16x8 h0, l0, h1, l1;
#pragma unroll
        for (int j = 0; j < 8; ++j) {
            float v0 = e0[j] * mk0;
            xn0 = fmaf(v0, v0, xn0);
            unsigned short hh0 = f2bf(v0);
            h0[j] = (short)hh0;
            l0[j] = (short)f2bf(v0 - bf2f(hh0));
            float v1 = e1[j] * mk1;
            xn1 = fmaf(v1, v1, xn1);
            unsigned short hh1 = f2bf(v1);
            h1[j] = (short)hh1;
            l1[j] = (short)f2bf(v1 - bf2f(hh1));
        }
        ah0[ks] = h0; al0[ks] = l0; ah1[ks] = h1; al1[ks] = l1;
    }
    xn0 += __shfl_xor(xn0, 16, 64);
    xn0 += __shfl_xor(xn0, 32, 64);
    xn1 += __shfl_xor(xn1, 16, 64);
    xn1 += __shfl_xor(xn1, 32, 64);
    if (kg == 0) {
        xnS[wid][m] = xn0; mkS[wid][m] = mk0;
        xnS[wid][16 + m] = xn1; mkS[wid][16 + m] = mk1;
    }

    float b1[2][4], b2[2][4];
    int bi[2][4];
#pragma unroll
    for (int tt = 0; tt < 2; ++tt)
#pragma unroll
        for (int r = 0; r < 4; ++r) {
            b1[tt][r] = 3.4e38f; b2[tt][r] = 3.4e38f; bi[tt][r] = 0x7fffffff;
        }

    int mo = tid >> 4, sl = tid & 15;
    int dstIdx = mo * 128 + (sl >> 3) * 64 + ((sl & 7) ^ (mo & 7)) * 8;  // ushorts
    float4 sh0, sv0, sh1, sv1;
#define LOADREGS(t)                                                            \
    {                                                                          \
        sh0 = *reinterpret_cast<const float4*>(                                \
            ebh + (size_t)((t) * 32 + mo) * D_EMB + sl * 8);                   \
        sv0 = *reinterpret_cast<const float4*>(                                \
            ebl + (size_t)((t) * 32 + mo) * D_EMB + sl * 8);                   \
        sh1 = *reinterpret_cast<const float4*>(                                \
            ebh + (size_t)((t) * 32 + 16 + mo) * D_EMB + sl * 8);              \
        sv1 = *reinterpret_cast<const float4*>(                                \
            ebl + (size_t)((t) * 32 + 16 + mo) * D_EMB + sl * 8);              \
    }
#define WRITEB(b)                                                              \
    {                                                                          \
        *reinterpret_cast<float4*>(&hb[b][dstIdx]) = sh0;                      \
        *reinterpret_cast<float4*>(&lb[b][dstIdx]) = sv0;                      \
        *reinterpret_cast<float4*>(&hb[b][2048 + dstIdx]) = sh1;               \
        *reinterpret_cast<float4*>(&lb[b][2048 + dstIdx]) = sv1;               \
    }

    LOADREGS(0);
    WRITEB(0);
    __syncthreads();
    for (int t = 0; t < 16; ++t) {
        int cur = t & 1;
        if (t < 15) LOADREGS(t + 1);   // issue early (T14)
#pragma unroll
        for (int sub = 0; sub < 2; ++sub) {
            bf16x8 bh[4], bl[4];
#pragma unroll
            for (int ks = 0; ks < 4; ++ks) {
                int off = sub * 2048 + m * 128 + (ks >> 1) * 64 +
                          ((((ks & 1) * 4 + kg)) ^ (m & 7)) * 8;
                bh[ks] = *reinterpret_cast<const bf16x8*>(&hb[cur][off]);
                bl[ks] = *reinterpret_cast<const bf16x8*>(&lb[cur][off]);
            }
            f32x4 accA0 = {0.f, 0.f, 0.f, 0.f}, accB0 = {0.f, 0.f, 0.f, 0.f};
            f32x4 accA1 = {0.f, 0.f, 0.f, 0.f}, accB1 = {0.f, 0.f, 0.f, 0.f};
#pragma unroll
            for (int ks = 0; ks < 2; ++ks) {
                accA0 = __builtin_amdgcn_mfma_f32_16x16x32_bf16(ah0[ks], bh[ks], accA0, 0, 0, 0);
                accA0 = __builtin_amdgcn_mfma_f32_16x16x32_bf16(al0[ks], bh[ks], accA0, 0, 0, 0);
                accA0 = __builtin_amdgcn_mfma_f32_16x16x32_bf16(ah0[ks], bl[ks], accA0, 0, 0, 0);
                accA1 = __builtin_amdgcn_mfma_f32_16x16x32_bf16(ah1[ks], bh[ks], accA1, 0, 0, 0);
                accA1 = __builtin_amdgcn_mfma_f32_16x16x32_bf16(al1[ks], bh[ks], accA1, 0, 0, 0);
                accA1 = __builtin_amdgcn_mfma_f32_16x16x32_bf16(ah1[ks], bl[ks], accA1, 0, 0, 0);
            }
#pragma unroll
            for (int ks = 2; ks < 4; ++ks) {
                accB0 = __builtin_amdgcn_mfma_f32_16x16x32_bf16(ah0[ks], bh[ks], accB0, 0, 0, 0);
                accB0 = __builtin_amdgcn_mfma_f32_16x16x32_bf16(al0[ks], bh[ks], accB0, 0, 0, 0);
                accB0 = __builtin_amdgcn_mfma_f32_16x16x32_bf16(ah0[ks], bl[ks], accB0, 0, 0, 0);
                accB1 = __builtin_amdgcn_mfma_f32_16x16x32_bf16(ah1[ks], bh[ks], accB1, 0, 0, 0);
                accB1 = __builtin_amdgcn_mfma_f32_16x16x32_bf16(al1[ks], bh[ks], accB1, 0, 0, 0);
                accB1 = __builtin_amdgcn_mfma_f32_16x16x32_bf16(ah1[ks], bl[ks], accB1, 0, 0, 0);
            }
            int c = t * 32 + sub * 16 + m;
            float sE = sumE[c];
#pragma unroll
            for (int r = 0; r < 4; ++r) {
                float s0 = fmaf(-2.f, accA0[r] + accB0[r], sE);
                if (s0 < b1[0][r]) { b2[0][r] = b1[0][r]; b1[0][r] = s0; bi[0][r] = c; }
                else if (s0 < b2[0][r]) b2[0][r] = s0;
                float s1 = fmaf(-2.f, accA1[r] + accB1[r], sE);
                if (s1 < b1[1][r]) { b2[1][r] = b1[1][r]; b1[1][r] = s1; bi[1][r] = c; }
                else if (s1 < b2[1][r]) b2[1][r] = s1;
            }
        }
        if (t < 15) WRITEB(cur ^ 1);   // write late
        __syncthreads();
    }
#undef LOADREGS
#undef WRITEB
#pragma unroll
    for (int off = 1; off <= 8; off <<= 1) {
#pragma unroll
        for (int tt = 0; tt < 2; ++tt)
#pragma unroll
            for (int r = 0; r < 4; ++r) {
                float o1 = __shfl_xor(b1[tt][r], off, 64);
                float o2 = __shfl_xor(b2[tt][r], off, 64);
                int oi = __shfl_xor(bi[tt][r], off, 64);
                if (o1 < b1[tt][r] || (o1 == b1[tt][r] && oi < bi[tt][r])) {
                    b2[tt][r] = fminf(b1[tt][r], o2); b1[tt][r] = o1; bi[tt][r] = oi;
                } else {
                    b2[tt][r] = fminf(b2[tt][r], o1);
                }
            }
    }
    float liS = 0.f, mkT = 0.f;
#pragma unroll
    for (int tt = 0; tt < 2; ++tt)
#pragma unroll
        for (int r = 0; r < 4; ++r) {
            int row = kg * 4 + r;
            float mkr = mkS[wid][tt * 16 + row], xnr = xnS[wid][tt * 16 + row];
            liS += mkr * mkr * (xnr + b1[tt][r]);
            mkT += mkr;
            if (m == 0) {
                int tokr = tok0 + tt * 16 + row;
                idx_out[tokr] = bi[tt][r];
                if (b2[tt][r] - b1[tt][r] < MARGIN) {
                    int pp = atomicAdd(flagCnt, 1);
                    flagList[pp] = tokr;
                }
            }
        }
    liS += __shfl_xor(liS, 16, 64);
    liS += __shfl_xor(liS, 32, 64);
    mkT += __shfl_xor(mkT, 16, 64);
    mkT += __shfl_xor(mkT, 32, 64);
    if (lane == 0) {
        int grp = blockIdx.x * 4 + wid;
        lossW[grp] = liS;
        maskW[grp] = mkT;
    }
}

// kF: bit-exact np-f32 rescan, one token per wave. (R21-validated.)
__global__ __launch_bounds__(256) void kF(const float* __restrict__ x,
                                          const float* __restrict__ xmask,
                                          const float* __restrict__ embT,
                                          const float* __restrict__ sumE,
                                          const int* __restrict__ flagCnt,
                                          const int* __restrict__ flagList,
                                          int* __restrict__ idx_out) {
    int wave = (blockIdx.x * 256 + threadIdx.x) >> 6;
    int lane = threadIdx.x & 63;
    int nW = gridDim.x * 4;
    int cnt = *flagCnt;
    for (int j = wave; j < cnt; j += nW) {
        int t = flagList[j];
        float mk = xmask[t];
        const float* xr = x + (size_t)t * D_EMB;
        float sx = np_pairwise_sumsq128(xr, mk);
        float acc[8];
#pragma unroll
        for (int cb = 0; cb < 8; ++cb) acc[cb] = 0.f;
        for (int i = 0; i < D_EMB; ++i) {
            float xi = __fmul_rn(xr[i], mk);
#pragma unroll
            for (int cb = 0; cb < 8; ++cb)
                acc[cb] = __fmaf_rn(xi, embT[i * M_CODES + cb * 64 + lane], acc[cb]);
        }
        float best = 3.4e38f;
        int bq = 0x7fffffff;
#pragma unroll
        for (int cb = 0; cb < 8; ++cb) {
            int c = cb * 64 + lane;
            float d = __fsub_rn(__fadd_rn(sumE[c], sx), __fmul_rn(2.f, acc[cb]));
            if (d < best || (d == best && c < bq)) { best = d; bq = c; }
        }
#pragma unroll
        for (int off = 32; off > 0; off >>= 1) {
            float s2 = __shfl_xor(best, off, 64);
            int i2 = __shfl_xor(bq, off, 64);
            if (s2 < best || (s2 == best && i2 < bq)) { best = s2; bq = i2; }
        }
        if (lane == 0) idx_out[t] = bq;
    }
}

// kScat v4 (R23 redesign): fused q_st gather + LDS scatter. Block = (dim-slice
// q of 32 dims, SCHUNK-token chunk), 1024 threads. idx/mask staged in LDS
// first (R23: VGPR=8 serialized the idx->x chain -> x read at 700 GB/s);
// x/emb reads + q_st writes are 128 B line-aligned contiguous per token.
// accD stride 513 de-aliases the per-dl bank pattern on LDS atomics.
__global__ __launch_bounds__(1024) void kScat(const float* __restrict__ x,
                                              const float* __restrict__ emb,
                                              const float* __restrict__ xmask,
                                              const int* __restrict__ idx,
                                              float* __restrict__ q_st,
                                              float* __restrict__ partialD,
                                              float* __restrict__ accc,
                                              int N, int nch) {
    __shared__ float accD[32 * ADSTRIDE];   // 65.7 KB
    __shared__ int idxL[SCHUNK];            // 4 KB
    __shared__ float mkL[SCHUNK];           // 4 KB
    __shared__ float accC[M_CODES];         // 2 KB
    int bid = blockIdx.x;
    int q = bid / nch, ch = bid - q * nch;  // q = dim-slice 0..3
    int tid = threadIdx.x;
    for (int i = tid; i < 32 * ADSTRIDE; i += 1024) accD[i] = 0.f;
    if (q == 0)
        for (int i = tid; i < M_CODES; i += 1024) accC[i] = 0.f;
    int base = ch * SCHUNK;
    // stage idx/mask (coalesced; one element per thread)
    idxL[tid] = idx[base + tid];
    mkL[tid] = xmask[base + tid];
    __syncthreads();
    if (q == 0) atomicAdd(&accC[idxL[tid]], 1.f);
    int tl = tid >> 3, dl = tid & 7;        // 128 tokens x 8 float4-lanes
    for (int it = 0; it < SCHUNK / 128; ++it) {
        int t = it * 128 + tl;
        int id = idxL[t];
        float mk = mkL[t];
        size_t fo = (size_t)(base + t) * D4 + q * 8 + dl;
        float4 xv = reinterpret_cast<const float4*>(x)[fo];
        float4 ev = reinterpret_cast<const float4*>(emb)[(size_t)id * D4 + q * 8 + dl];
        float4 o;
        o.x = ev.x * mk; o.y = ev.y * mk; o.z = ev.z * mk; o.w = ev.w * mk;
        reinterpret_cast<float4*>(q_st)[fo] = o;
        int d0 = dl * 4;
        atomicAdd(&accD[(d0 + 0) * ADSTRIDE + id], xv.x * mk);
        atomicAdd(&accD[(d0 + 1) * ADSTRIDE + id], xv.y * mk);
        atomicAdd(&accD[(d0 + 2) * ADSTRIDE + id], xv.z * mk);
        atomicAdd(&accD[(d0 + 3) * ADSTRIDE + id], xv.w * mk);
    }
    __syncthreads();
    float* pD = partialD + (size_t)bid * (32 * M_CODES);
    for (int i = tid; i < 32 * M_CODES; i += 1024) {
        int dd = i >> 9, c = i & 511;
        pD[i] = accD[dd * ADSTRIDE + c];
    }
    if (q == 0)
        for (int i = tid; i < M_CODES; i += 1024) atomicAdd(&accc[i], accC[i]);
}

// kWD2: fused finalize (R22-validated; indexing for 4 slices x 32 dims).
__global__ __launch_bounds__(256) void kWD2(const float* __restrict__ partialD,
                                            const float* __restrict__ ema_w,
                                            const float* __restrict__ counts,
                                            const float* __restrict__ ema_count,
                                            const float* __restrict__ lossP,
                                            const float* __restrict__ maskP,
                                            float* __restrict__ new_w,
                                            float* __restrict__ new_emb,
                                            float* __restrict__ new_cnt,
                                            float* __restrict__ loss_out,
                                            int nch, int nP) {
    __shared__ float red[256];
    int tid = threadIdx.x;
    float part = 0.999f * ema_count[tid] + 0.001f * counts[tid];
    part += 0.999f * ema_count[tid + 256] + 0.001f * counts[tid + 256];
    red[tid] = part;
    __syncthreads();
#pragma unroll
    for (int s = 128; s > 0; s >>= 1) {
        if (tid < s) red[tid] += red[tid + s];
        __syncthreads();
    }
    float nsum = red[0];
    __syncthreads();

    int i = blockIdx.x * 256 + tid;   // 65536 elements
    int c = i & 511;                  // code (fastest)
    int d = i >> 9;                   // dim 0..127
    int q = d >> 5, dd = d & 31;
    float raw = 0.999f * ema_count[c] + 0.001f * counts[c];
    float norm = (raw + 1e-5f) / (nsum + (float)M_CODES * 1e-5f) * nsum;
    float s = 0.f;
    for (int ch = 0; ch < nch; ++ch)
        s += partialD[(size_t)(q * nch + ch) * (32 * M_CODES) + dd * M_CODES + c];
    size_t o = (size_t)c * D_EMB + d;
    float w = 0.999f * ema_w[o] + 0.001f * s;
    new_w[o] = w;
    new_emb[o] = w / norm;
    if (d == 0) new_cnt[c] = norm;

    if (blockIdx.x == 0) {
        float lp = 0.f, mp = 0.f;
        for (int j = tid; j < nP; j += 256) { lp += lossP[j]; mp += maskP[j]; }
        red[tid] = lp;
        __syncthreads();
#pragma unroll
        for (int ss = 128; ss > 0; ss >>= 1) {
            if (tid < ss) red[tid] += red[tid + ss];
            __syncthreads();
        }
        float S = red[0];
        __syncthreads();
        red[tid] = mp;
        __syncthreads();
#pragma unroll
        for (int ss = 128; ss > 0; ss >>= 1) {
            if (tid < ss) red[tid] += red[tid + ss];
            __syncthreads();
        }
        if (tid == 0) loss_out[0] = 0.25f * S / (red[0] * (float)D_EMB);
    }
}

extern "C" void kernel_launch(void* const* d_in, const int* in_sizes, int n_in,
                              void* d_out, int out_size, void* d_ws, size_t ws_size,
                              hipStream_t stream) {
    const float* x = (const float*)d_in[0];
    const float* xmask = (const float*)d_in[1];
    const float* emb = (const float*)d_in[2];
    const float* ema_count = (const float*)d_in[3];
    const float* ema_weight = (const float*)d_in[4];
    int N = in_sizes[0] / D_EMB;

    float* out = (float*)d_out;
    float* q_st = out;
    float* loss = out + (size_t)N * D_EMB;
    float* new_emb = loss + 1;
    float* new_cnt = new_emb + M_CODES * D_EMB;
    float* new_w = new_cnt + M_CODES;

    int nGrp = N / 32;                         // 2048 wave groups
    int nch = (N + SCHUNK - 1) / SCHUNK;       // 64
    float* fws = (float*)d_ws;
    int* idx = (int*)fws;                      // N
    float* counts = fws + N;                   // 512 (accc)
    float* norm = counts + M_CODES;            // 512 (layout keep)
    float* lossP = norm + M_CODES;             // nGrp
    float* maskP = lossP + nGrp;               // nGrp
    float* sumE = maskP + nGrp;                // 512
    int* flagCnt = (int*)(sumE + M_CODES);     // 4
    int* flagList = flagCnt + 4;               // N
    float* embT = (float*)(flagList + N);      // 65536
    unsigned short* ebh = (unsigned short*)(embT + M_CODES * D_EMB);  // 65536 u16
    unsigned short* ebl = ebh + M_CODES * D_EMB;                      // 65536 u16
    float* partialD = (float*)(ebl + M_CODES * D_EMB);  // 4*nch*32*512 f32 (16MB)

    hipLaunchKernelGGL(kSZ, dim3(128), dim3(256), 0, stream,
                       emb, sumE, embT, ebh, ebl, counts, flagCnt);
    hipLaunchKernelGGL(kA, dim3(N / 128), dim3(256), 0, stream, x, xmask, ebh,
                       ebl, sumE, idx, flagCnt, flagList, lossP, maskP, N);
    hipLaunchKernelGGL(kF, dim3(1024), dim3(256), 0, stream, x, xmask, embT, sumE,
                       flagCnt, flagList, idx);
    hipLaunchKernelGGL(kScat, dim3(4 * nch), dim3(1024), 0, stream, x, emb,
                       xmask, idx, q_st, partialD, counts, N, nch);
    hipLaunchKernelGGL(kWD2, dim3(M_CODES * D_EMB / 256), dim3(256), 0, stream,
                       partialD, ema_weight, counts, ema_count, lossP, maskP,
                       new_w, new_emb, new_cnt, loss, nch, nGrp);
}

// Round 25
// 122.050 us; speedup vs baseline: 1.1639x; 1.1075x over previous
//
#include <hip/hip_runtime.h>

#define M_CODES 512
#define D_EMB 128
#define D4 32
#define MARGIN 5e-5f
#define SCHUNK 1024

typedef short bf16x8 __attribute__((ext_vector_type(8)));
typedef float f32x4 __attribute__((ext_vector_type(4)));

__device__ __forceinline__ unsigned short f2bf(float f) {  // RNE f32->bf16
    unsigned u = __float_as_uint(f);
    u += 0x7fffu + ((u >> 16) & 1u);
    return (unsigned short)(u >> 16);
}
__device__ __forceinline__ float bf2f(unsigned short h) {
    return __uint_as_float(((unsigned)h) << 16);
}

// numpy pairwise sum (n=128): 8 strided accumulators + tree. (R6-validated.)
__device__ __forceinline__ float np_pairwise_sumsq128(const float* __restrict__ a,
                                                      float scale) {
    float r[8];
#pragma unroll
    for (int j = 0; j < 8; ++j) {
        float v = __fmul_rn(a[j], scale);
        r[j] = __fmul_rn(v, v);
    }
    for (int i = 8; i < 128; i += 8) {
#pragma unroll
        for (int j = 0; j < 8; ++j) {
            float v = __fmul_rn(a[i + j], scale);
            r[j] = __fadd_rn(r[j], __fmul_rn(v, v));
        }
    }
    return __fadd_rn(__fadd_rn(__fadd_rn(r[0], r[1]), __fadd_rn(r[2], r[3])),
                     __fadd_rn(__fadd_rn(r[4], r[5]), __fadd_rn(r[6], r[7])));
}

// kSZ: parallel setup (R17-validated) + zero gcnt/flagCnt.
__global__ __launch_bounds__(256) void kSZ(const float* __restrict__ emb,
                                           float* __restrict__ sumE,
                                           float* __restrict__ embT,
                                           unsigned short* __restrict__ ebh,
                                           unsigned short* __restrict__ ebl,
                                           int* __restrict__ gcnt,
                                           int* __restrict__ flagCnt) {
    int tid = threadIdx.x, wid = tid >> 6, lane = tid & 63;
    int m = blockIdx.x * 4 + wid;            // 0..511
    int gi = blockIdx.x * 256 + tid;
    if (gi < M_CODES) gcnt[gi] = 0;
    if (gi == 0) *flagCnt = 0;
    const float* er = emb + (size_t)m * D_EMB;
    float r = 0.f;
    if (lane < 8) {
        float v = __fmul_rn(er[lane], 1.0f);
        r = __fmul_rn(v, v);
        for (int i = 1; i < 16; ++i) {
            float w = __fmul_rn(er[8 * i + lane], 1.0f);
            r = __fadd_rn(r, __fmul_rn(w, w));
        }
    }
    float s1 = __fadd_rn(r, __shfl_xor(r, 1, 64));
    float s2 = __fadd_rn(s1, __shfl_xor(s1, 2, 64));
    float s3 = __fadd_rn(s2, __shfl_xor(s2, 4, 64));
    if (lane == 0) sumE[m] = s3;
#pragma unroll
    for (int dd = lane; dd < D_EMB; dd += 64) {
        float e = er[dd];
        embT[dd * M_CODES + m] = e;
        unsigned short hh = f2bf(e);
        ebh[(size_t)m * D_EMB + dd] = hh;
        ebl[(size_t)m * D_EMB + dd] = f2bf(e - bf2f(hh));
    }
}

// kA: split-bf16 MFMA + LDS-staged codebook, 32-code tiles + T14 async-stage
// split. (R22-validated.)
__global__ __launch_bounds__(256) void kA(const float* __restrict__ x,
                                          const float* __restrict__ xmask,
                                          const unsigned short* __restrict__ ebh,
                                          const unsigned short* __restrict__ ebl,
                                          const float* __restrict__ sumE,
                                          int* __restrict__ idx_out,
                                          int* __restrict__ flagCnt,
                                          int* __restrict__ flagList,
                                          float* __restrict__ lossW,
                                          float* __restrict__ maskW, int N) {
    __shared__ unsigned short hb[2][4096];   // 8 KB per buf: 32 codes x 128d
    __shared__ unsigned short lb[2][4096];
    __shared__ float xnS[4][32], mkS[4][32];
    int tid = threadIdx.x;
    int wid = tid >> 6, lane = tid & 63;
    int m = lane & 15, kg = lane >> 4;
    int tok0 = blockIdx.x * 128 + wid * 32;

    bf16x8 ah0[4], al0[4], ah1[4], al1[4];
    float xn0 = 0.f, xn1 = 0.f;
    float mk0 = xmask[tok0 + m], mk1 = xmask[tok0 + 16 + m];
#pragma unroll
    for (int ks = 0; ks < 4; ++ks) {
        const float4* p0 = reinterpret_cast<const float4*>(
            x + (size_t)(tok0 + m) * D_EMB + ks * 32 + kg * 8);
        const float4* p1 = reinterpret_cast<const float4*>(
            x + (size_t)(tok0 + 16 + m) * D_EMB + ks * 32 + kg * 8);
        float4 a0 = p0[0], a1 = p0[1], c0 = p1[0], c1 = p1[1];
        float e0[8] = {a0.x, a0.y, a0.z, a0.w, a1.x, a1.y, a1.z, a1.w};
        float e1[8] = {c0.x, c0.y, c0.z, c0.w, c1.x, c1.y, c1.z, c1.w};
        bf16x8 h0, l0, h1, l1;
#pragma unroll
        for (int j = 0; j < 8; ++j) {
            float v0 = e0[j] * mk0;
            xn0 = fmaf(v0, v0, xn0);
            unsigned short hh0 = f2bf(v0);
            h0[j] = (short)hh0;
            l0[j] = (short)f2bf(v0 - bf2f(hh0));
            float v1 = e1[j] * mk1;
            xn1 = fmaf(v1, v1, xn1);
            unsigned short hh1 = f2bf(v1);
            h1[j] = (short)hh1;
            l1[j] = (short)f2bf(v1 - bf2f(hh1));
        }
        ah0[ks] = h0; al0[ks] = l0; ah1[ks] = h1; al1[ks] = l1;
    }
    xn0 += __shfl_xor(xn0, 16, 64);
    xn0 += __shfl_xor(xn0, 32, 64);
    xn1 += __shfl_xor(xn1, 16, 64);
    xn1 += __shfl_xor(xn1, 32, 64);
    if (kg == 0) {
        xnS[wid][m] = xn0; mkS[wid][m] = mk0;
        xnS[wid][16 + m] = xn1; mkS[wid][16 + m] = mk1;
    }

    float b1[2][4], b2[2][4];
    int bi[2][4];
#pragma unroll
    for (int tt = 0; tt < 2; ++tt)
#pragma unroll
        for (int r = 0; r < 4; ++r) {
            b1[tt][r] = 3.4e38f; b2[tt][r] = 3.4e38f; bi[tt][r] = 0x7fffffff;
        }

    int mo = tid >> 4, sl = tid & 15;
    int dstIdx = mo * 128 + (sl >> 3) * 64 + ((sl & 7) ^ (mo & 7)) * 8;  // ushorts
    float4 sh0, sv0, sh1, sv1;
#define LOADREGS(t)                                                            \
    {                                                                          \
        sh0 = *reinterpret_cast<const float4*>(                                \
            ebh + (size_t)((t) * 32 + mo) * D_EMB + sl * 8);                   \
        sv0 = *reinterpret_cast<const float4*>(                                \
            ebl + (size_t)((t) * 32 + mo) * D_EMB + sl * 8);                   \
        sh1 = *reinterpret_cast<const float4*>(                                \
            ebh + (size_t)((t) * 32 + 16 + mo) * D_EMB + sl * 8);              \
        sv1 = *reinterpret_cast<const float4*>(                                \
            ebl + (size_t)((t) * 32 + 16 + mo) * D_EMB + sl * 8);              \
    }
#define WRITEB(b)                                                              \
    {                                                                          \
        *reinterpret_cast<float4*>(&hb[b][dstIdx]) = sh0;                      \
        *reinterpret_cast<float4*>(&lb[b][dstIdx]) = sv0;                      \
        *reinterpret_cast<float4*>(&hb[b][2048 + dstIdx]) = sh1;               \
        *reinterpret_cast<float4*>(&lb[b][2048 + dstIdx]) = sv1;               \
    }

    LOADREGS(0);
    WRITEB(0);
    __syncthreads();
    for (int t = 0; t < 16; ++t) {
        int cur = t & 1;
        if (t < 15) LOADREGS(t + 1);   // issue early (T14)
#pragma unroll
        for (int sub = 0; sub < 2; ++sub) {
            bf16x8 bh[4], bl[4];
#pragma unroll
            for (int ks = 0; ks < 4; ++ks) {
                int off = sub * 2048 + m * 128 + (ks >> 1) * 64 +
                          ((((ks & 1) * 4 + kg)) ^ (m & 7)) * 8;
                bh[ks] = *reinterpret_cast<const bf16x8*>(&hb[cur][off]);
                bl[ks] = *reinterpret_cast<const bf16x8*>(&lb[cur][off]);
            }
            f32x4 accA0 = {0.f, 0.f, 0.f, 0.f}, accB0 = {0.f, 0.f, 0.f, 0.f};
            f32x4 accA1 = {0.f, 0.f, 0.f, 0.f}, accB1 = {0.f, 0.f, 0.f, 0.f};
#pragma unroll
            for (int ks = 0; ks < 2; ++ks) {
                accA0 = __builtin_amdgcn_mfma_f32_16x16x32_bf16(ah0[ks], bh[ks], accA0, 0, 0, 0);
                accA0 = __builtin_amdgcn_mfma_f32_16x16x32_bf16(al0[ks], bh[ks], accA0, 0, 0, 0);
                accA0 = __builtin_amdgcn_mfma_f32_16x16x32_bf16(ah0[ks], bl[ks], accA0, 0, 0, 0);
                accA1 = __builtin_amdgcn_mfma_f32_16x16x32_bf16(ah1[ks], bh[ks], accA1, 0, 0, 0);
                accA1 = __builtin_amdgcn_mfma_f32_16x16x32_bf16(al1[ks], bh[ks], accA1, 0, 0, 0);
                accA1 = __builtin_amdgcn_mfma_f32_16x16x32_bf16(ah1[ks], bl[ks], accA1, 0, 0, 0);
            }
#pragma unroll
            for (int ks = 2; ks < 4; ++ks) {
                accB0 = __builtin_amdgcn_mfma_f32_16x16x32_bf16(ah0[ks], bh[ks], accB0, 0, 0, 0);
                accB0 = __builtin_amdgcn_mfma_f32_16x16x32_bf16(al0[ks], bh[ks], accB0, 0, 0, 0);
                accB0 = __builtin_amdgcn_mfma_f32_16x16x32_bf16(ah0[ks], bl[ks], accB0, 0, 0, 0);
                accB1 = __builtin_amdgcn_mfma_f32_16x16x32_bf16(ah1[ks], bh[ks], accB1, 0, 0, 0);
                accB1 = __builtin_amdgcn_mfma_f32_16x16x32_bf16(al1[ks], bh[ks], accB1, 0, 0, 0);
                accB1 = __builtin_amdgcn_mfma_f32_16x16x32_bf16(ah1[ks], bl[ks], accB1, 0, 0, 0);
            }
            int c = t * 32 + sub * 16 + m;
            float sE = sumE[c];
#pragma unroll
            for (int r = 0; r < 4; ++r) {
                float s0 = fmaf(-2.f, accA0[r] + accB0[r], sE);
                if (s0 < b1[0][r]) { b2[0][r] = b1[0][r]; b1[0][r] = s0; bi[0][r] = c; }
                else if (s0 < b2[0][r]) b2[0][r] = s0;
                float s1 = fmaf(-2.f, accA1[r] + accB1[r], sE);
                if (s1 < b1[1][r]) { b2[1][r] = b1[1][r]; b1[1][r] = s1; bi[1][r] = c; }
                else if (s1 < b2[1][r]) b2[1][r] = s1;
            }
        }
        if (t < 15) WRITEB(cur ^ 1);   // write late
        __syncthreads();
    }
#undef LOADREGS
#undef WRITEB
#pragma unroll
    for (int off = 1; off <= 8; off <<= 1) {
#pragma unroll
        for (int tt = 0; tt < 2; ++tt)
#pragma unroll
            for (int r = 0; r < 4; ++r) {
                float o1 = __shfl_xor(b1[tt][r], off, 64);
                float o2 = __shfl_xor(b2[tt][r], off, 64);
                int oi = __shfl_xor(bi[tt][r], off, 64);
                if (o1 < b1[tt][r] || (o1 == b1[tt][r] && oi < bi[tt][r])) {
                    b2[tt][r] = fminf(b1[tt][r], o2); b1[tt][r] = o1; bi[tt][r] = oi;
                } else {
                    b2[tt][r] = fminf(b2[tt][r], o1);
                }
            }
    }
    float liS = 0.f, mkT = 0.f;
#pragma unroll
    for (int tt = 0; tt < 2; ++tt)
#pragma unroll
        for (int r = 0; r < 4; ++r) {
            int row = kg * 4 + r;
            float mkr = mkS[wid][tt * 16 + row], xnr = xnS[wid][tt * 16 + row];
            liS += mkr * mkr * (xnr + b1[tt][r]);
            mkT += mkr;
            if (m == 0) {
                int tokr = tok0 + tt * 16 + row;
                idx_out[tokr] = bi[tt][r];
                if (b2[tt][r] - b1[tt][r] < MARGIN) {
                    int pp = atomicAdd(flagCnt, 1);
                    flagList[pp] = tokr;
                }
            }
        }
    liS += __shfl_xor(liS, 16, 64);
    liS += __shfl_xor(liS, 32, 64);
    mkT += __shfl_xor(mkT, 16, 64);
    mkT += __shfl_xor(mkT, 32, 64);
    if (lane == 0) {
        int grp = blockIdx.x * 4 + wid;
        lossW[grp] = liS;
        maskW[grp] = mkT;
    }
}

// kF: bit-exact np-f32 rescan, one token per wave. (R21-validated.)
__global__ __launch_bounds__(256) void kF(const float* __restrict__ x,
                                          const float* __restrict__ xmask,
                                          const float* __restrict__ embT,
                                          const float* __restrict__ sumE,
                                          const int* __restrict__ flagCnt,
                                          const int* __restrict__ flagList,
                                          int* __restrict__ idx_out) {
    int wave = (blockIdx.x * 256 + threadIdx.x) >> 6;
    int lane = threadIdx.x & 63;
    int nW = gridDim.x * 4;
    int cnt = *flagCnt;
    for (int j = wave; j < cnt; j += nW) {
        int t = flagList[j];
        float mk = xmask[t];
        const float* xr = x + (size_t)t * D_EMB;
        float sx = np_pairwise_sumsq128(xr, mk);
        float acc[8];
#pragma unroll
        for (int cb = 0; cb < 8; ++cb) acc[cb] = 0.f;
        for (int i = 0; i < D_EMB; ++i) {
            float xi = __fmul_rn(xr[i], mk);
#pragma unroll
            for (int cb = 0; cb < 8; ++cb)
                acc[cb] = __fmaf_rn(xi, embT[i * M_CODES + cb * 64 + lane], acc[cb]);
        }
        float best = 3.4e38f;
        int bq = 0x7fffffff;
#pragma unroll
        for (int cb = 0; cb < 8; ++cb) {
            int c = cb * 64 + lane;
            float d = __fsub_rn(__fadd_rn(sumE[c], sx), __fmul_rn(2.f, acc[cb]));
            if (d < best || (d == best && c < bq)) { best = d; bq = c; }
        }
#pragma unroll
        for (int off = 32; off > 0; off >>= 1) {
            float s2 = __shfl_xor(best, off, 64);
            int i2 = __shfl_xor(bq, off, 64);
            if (s2 < best || (s2 == best && i2 < bq)) { best = s2; bq = i2; }
        }
        if (lane == 0) idx_out[t] = bq;
    }
}

// kHist: per-chunk LDS histogram -> 512 global int adds per block.
__global__ __launch_bounds__(1024) void kHist(const int* __restrict__ idx,
                                              int* __restrict__ gcnt) {
    __shared__ int h[M_CODES];
    int tid = threadIdx.x;
    if (tid < M_CODES) h[tid] = 0;
    __syncthreads();
    atomicAdd(&h[idx[blockIdx.x * 1024 + tid]], 1);
    __syncthreads();
    if (tid < M_CODES && h[tid] > 0) atomicAdd(&gcnt[tid], h[tid]);
}

// kPfx: 1 block. Exclusive scan of gcnt -> offs+cursor; nsum/norm/new_cnt;
// loss finalize (absorbs old kC/kWD2 serial parts).
__global__ __launch_bounds__(512) void kPfx(const int* __restrict__ gcnt,
                                            const float* __restrict__ ema_count,
                                            int* __restrict__ offs,
                                            int* __restrict__ cursor,
                                            float* __restrict__ normv,
                                            float* __restrict__ new_cnt,
                                            const float* __restrict__ lossP,
                                            const float* __restrict__ maskP,
                                            float* __restrict__ loss_out, int nP) {
    __shared__ int sc[M_CODES];
    __shared__ float red[M_CODES];
    int tid = threadIdx.x;
    int c = gcnt[tid];
    sc[tid] = c;
    __syncthreads();
    for (int off = 1; off < M_CODES; off <<= 1) {
        int v = (tid >= off) ? sc[tid - off] : 0;
        __syncthreads();
        sc[tid] += v;
        __syncthreads();
    }
    int excl = sc[tid] - c;
    offs[tid] = excl;
    cursor[tid] = excl;
    float raw = 0.999f * ema_count[tid] + 0.001f * (float)c;
    red[tid] = raw;
    __syncthreads();
#pragma unroll
    for (int s = 256; s > 0; s >>= 1) {
        if (tid < s) red[tid] += red[tid + s];
        __syncthreads();
    }
    float nsum = red[0];
    __syncthreads();
    float nrm = (raw + 1e-5f) / (nsum + (float)M_CODES * 1e-5f) * nsum;
    normv[tid] = nrm;
    new_cnt[tid] = nrm;
    float lp = 0.f, mp = 0.f;
    for (int j = tid; j < nP; j += 512) { lp += lossP[j]; mp += maskP[j]; }
    red[tid] = lp;
    __syncthreads();
#pragma unroll
    for (int s = 256; s > 0; s >>= 1) {
        if (tid < s) red[tid] += red[tid + s];
        __syncthreads();
    }
    float S = red[0];
    __syncthreads();
    red[tid] = mp;
    __syncthreads();
#pragma unroll
    for (int s = 256; s > 0; s >>= 1) {
        if (tid < s) red[tid] += red[tid + s];
        __syncthreads();
    }
    if (tid == 0) loss_out[0] = 0.25f * S / (red[0] * (float)D_EMB);
}

// kBucket: counting-sort scatter of token ids into per-code lists.
__global__ __launch_bounds__(1024) void kBucket(const int* __restrict__ idx,
                                                int* __restrict__ cursor,
                                                int* __restrict__ bucket) {
    __shared__ int lh[M_CODES];
    __shared__ int gb[M_CODES];
    int tid = threadIdx.x;
    if (tid < M_CODES) lh[tid] = 0;
    __syncthreads();
    int t = blockIdx.x * 1024 + tid;
    int c = idx[t];
    int r = atomicAdd(&lh[c], 1);
    __syncthreads();
    if (tid < M_CODES && lh[tid] > 0) gb[tid] = atomicAdd(&cursor[tid], lh[tid]);
    __syncthreads();
    bucket[gb[c] + r] = t;
}

// kAgg: block per code. Registers hold emb row; token ids+masks staged in LDS
// tiles; per token: one coalesced x-row read (dw accumulate, NO atomics) + one
// coalesced q_st row write. Epilogue: EMA + divide (kWD2 fused).
__global__ __launch_bounds__(256) void kAgg(const float* __restrict__ x,
                                            const float* __restrict__ xmask,
                                            const float* __restrict__ emb,
                                            const float* __restrict__ ema_w,
                                            const int* __restrict__ bucket,
                                            const int* __restrict__ offs,
                                            const int* __restrict__ gcnt,
                                            const float* __restrict__ normv,
                                            float* __restrict__ q_st,
                                            float* __restrict__ new_w,
                                            float* __restrict__ new_emb) {
    __shared__ int tokL[256];
    __shared__ float mkL[256];
    __shared__ float half1[D_EMB];
    int c = blockIdx.x;
    int tid = threadIdx.x;
    int d = tid & 127, par = tid >> 7;
    int off = offs[c], cnt = gcnt[c];
    float e = emb[(size_t)c * D_EMB + d];
    float dw = 0.f;
    for (int base = 0; base < cnt; base += 256) {
        int n = cnt - base;
        if (n > 256) n = 256;
        if (tid < n) {
            int t = bucket[off + base + tid];
            tokL[tid] = t;
            mkL[tid] = xmask[t];
        }
        __syncthreads();
        for (int i = par; i < n; i += 2) {
            int t = tokL[i];
            float mk = mkL[i];
            dw = fmaf(x[(size_t)t * D_EMB + d], mk, dw);
            q_st[(size_t)t * D_EMB + d] = e * mk;
        }
        __syncthreads();
    }
    if (par == 1) half1[d] = dw;
    __syncthreads();
    if (par == 0) {
        float s = dw + half1[d];
        size_t o = (size_t)c * D_EMB + d;
        float w = 0.999f * ema_w[o] + 0.001f * s;
        new_w[o] = w;
        new_emb[o] = w / normv[c];
    }
}

extern "C" void kernel_launch(void* const* d_in, const int* in_sizes, int n_in,
                              void* d_out, int out_size, void* d_ws, size_t ws_size,
                              hipStream_t stream) {
    const float* x = (const float*)d_in[0];
    const float* xmask = (const float*)d_in[1];
    const float* emb = (const float*)d_in[2];
    const float* ema_count = (const float*)d_in[3];
    const float* ema_weight = (const float*)d_in[4];
    int N = in_sizes[0] / D_EMB;

    float* out = (float*)d_out;
    float* q_st = out;
    float* loss = out + (size_t)N * D_EMB;
    float* new_emb = loss + 1;
    float* new_cnt = new_emb + M_CODES * D_EMB;
    float* new_w = new_cnt + M_CODES;

    int nGrp = N / 32;                         // 2048 wave groups
    int nch = N / 1024;                        // 64 chunks
    float* fws = (float*)d_ws;
    int* idx = (int*)fws;                      // N
    int* gcnt = idx + N;                       // 512
    int* offs = gcnt + M_CODES;                // 512
    int* cursor = offs + M_CODES;              // 512
    float* normv = (float*)(cursor + M_CODES); // 512
    float* lossP = normv + M_CODES;            // nGrp
    float* maskP = lossP + nGrp;               // nGrp
    float* sumE = maskP + nGrp;                // 512
    int* flagCnt = (int*)(sumE + M_CODES);     // 4
    int* flagList = flagCnt + 4;               // N
    int* bucket = flagList + N;                // N
    float* embT = (float*)(bucket + N);        // 65536
    unsigned short* ebh = (unsigned short*)(embT + M_CODES * D_EMB);  // 65536 u16
    unsigned short* ebl = ebh + M_CODES * D_EMB;                      // 65536 u16

    hipLaunchKernelGGL(kSZ, dim3(128), dim3(256), 0, stream,
                       emb, sumE, embT, ebh, ebl, gcnt, flagCnt);
    hipLaunchKernelGGL(kA, dim3(N / 128), dim3(256), 0, stream, x, xmask, ebh,
                       ebl, sumE, idx, flagCnt, flagList, lossP, maskP, N);
    hipLaunchKernelGGL(kF, dim3(1024), dim3(256), 0, stream, x, xmask, embT, sumE,
                       flagCnt, flagList, idx);
    hipLaunchKernelGGL(kHist, dim3(nch), dim3(1024), 0, stream, idx, gcnt);
    hipLaunchKernelGGL(kPfx, dim3(1), dim3(512), 0, stream, gcnt, ema_count,
                       offs, cursor, normv, new_cnt, lossP, maskP, loss, nGrp);
    hipLaunchKernelGGL(kBucket, dim3(nch), dim3(1024), 0, stream, idx, cursor,
                       bucket);
    hipLaunchKernelGGL(kAgg, dim3(M_CODES), dim3(256), 0, stream, x, xmask, emb,
                       ema_weight, bucket, offs, gcnt, normv, q_st, new_w,
                       new_emb);
}